// Round 5
// baseline (683.580 us; speedup 1.0000x reference)
//
#include <hip/hip_runtime.h>
#include <hip/hip_fp16.h>

// Problem constants: B=1, L=2048, C=2048, H=16, D=128, keys = 2L = 4096
#define LQ 2048
#define CDIM 2048
#define NHEAD 16
#define HDIM 128
#define LKEY 4096

typedef _Float16 f16x8 __attribute__((ext_vector_type(8)));
typedef float f32x4 __attribute__((ext_vector_type(4)));

#define GLOAD_LDS16(g, s) __builtin_amdgcn_global_load_lds( \
    (const __attribute__((address_space(1))) void*)(g),     \
    (__attribute__((address_space(3))) void*)(s), 16, 0, 0)

__device__ __forceinline__ void storeC(float* p, float v) { *p = v; }
__device__ __forceinline__ void storeC(__half* p, float v) { *p = __float2half(v); }
__device__ __forceinline__ float toF(float v) { return v; }
__device__ __forceinline__ float toF(__half v) { return __half2float(v); }

// ---------------------------------------------------------------------------
// C[128bm+0:128, 128bn+0:128] = A[*, 0:K] * B[*, 0:K]^T  (fp16 in, fp32 acc)
// generalized leading dims; 128x128 tile, BK=64, 4 waves, 4x4 acc/wave.
// ---------------------------------------------------------------------------
template <typename OutT>
__global__ __launch_bounds__(256, 2) void gemm_bt(
    const __half* __restrict__ A, const __half* __restrict__ B,
    OutT* __restrict__ C, int lda, int ldb, int ldc, int K)
{
    __shared__ __align__(16) __half lA[128 * 64];
    __shared__ __align__(16) __half lB[128 * 64];
    const int tid  = threadIdx.x;
    const int lane = tid & 63;
    const int wave = tid >> 6;
    const int bm = blockIdx.x, bn = blockIdx.y;
    const int r = tid >> 3;     // 0..31: row within 32-row staging slab
    const int g = tid & 7;      // 8-elem col group
    const __half* gA = A + (long)(bm * 128 + r) * lda + ((g ^ (r & 7)) << 3);
    const __half* gB = B + (long)(bn * 128 + r) * ldb + ((g ^ (r & 7)) << 3);
    __half* lAp = lA + tid * 8;
    __half* lBp = lB + tid * 8;
    const int wr = (wave & 1) << 6;
    const int wc = (wave >> 1) << 6;
    const int l15 = lane & 15, quad = lane >> 4;

    f32x4 acc[4][4] = {};

    for (int kt = 0; kt < K; kt += 64) {
#pragma unroll
        for (int i = 0; i < 4; ++i) {
            GLOAD_LDS16(gA + (long)i * 32 * lda, lAp + i * 2048);
            GLOAD_LDS16(gB + (long)i * 32 * ldb, lBp + i * 2048);
        }
        gA += 64; gB += 64;
        __syncthreads();
#pragma unroll
        for (int kk = 0; kk < 2; ++kk) {
            f16x8 af[4], bfr[4];
#pragma unroll
            for (int mi = 0; mi < 4; ++mi) {
                const int m = wr + mi * 16 + l15;
                const int kg = kk * 4 + quad;
                af[mi] = *(const f16x8*)&lA[m * 64 + ((kg ^ (m & 7)) << 3)];
            }
#pragma unroll
            for (int ni = 0; ni < 4; ++ni) {
                const int n = wc + ni * 16 + l15;
                const int kg = kk * 4 + quad;
                bfr[ni] = *(const f16x8*)&lB[n * 64 + ((kg ^ (n & 7)) << 3)];
            }
#pragma unroll
            for (int mi = 0; mi < 4; ++mi)
#pragma unroll
                for (int ni = 0; ni < 4; ++ni)
                    acc[mi][ni] = __builtin_amdgcn_mfma_f32_16x16x32_f16(
                        af[mi], bfr[ni], acc[mi][ni], 0, 0, 0);
        }
        __syncthreads();
    }
    const int row0 = bm * 128 + wr + quad * 4;
    const int col0 = bn * 128 + wc + l15;
#pragma unroll
    for (int mi = 0; mi < 4; ++mi)
#pragma unroll
        for (int ni = 0; ni < 4; ++ni)
#pragma unroll
            for (int rx = 0; rx < 4; ++rx)
                storeC(&C[(long)(row0 + mi * 16 + rx) * ldc + col0 + ni * 16],
                       acc[mi][ni][rx]);
}

// ---------------------------------------------------------------------------
// S-GEMM with exp2 epilogue: per head h (blockIdx.z):
//   P[h][q][key] = exp2( qf[q, h*128:..] . kvf[key, h*128:..] - 10 )  (fp16)
//   lsum[h][q] += row-sums (fp32 atomics)
// q was pre-scaled by log2(e)/sqrt(D); bias -10 keeps P in fp16 normal range.
// ---------------------------------------------------------------------------
__global__ __launch_bounds__(256, 2) void sgemm_exp(
    const __half* __restrict__ Qf, const __half* __restrict__ Kf,
    __half* __restrict__ P, float* __restrict__ lsum)
{
    __shared__ __align__(16) __half lA[128 * 64];
    __shared__ __align__(16) __half lB[128 * 64];
    const int tid  = threadIdx.x;
    const int lane = tid & 63;
    const int wave = tid >> 6;
    const int bm = blockIdx.x, bn = blockIdx.y, h = blockIdx.z;
    const int r = tid >> 3;
    const int g = tid & 7;
    const __half* gA = Qf + h * HDIM + (long)(bm * 128 + r) * CDIM + ((g ^ (r & 7)) << 3);
    const __half* gB = Kf + h * HDIM + (long)(bn * 128 + r) * 4096 + ((g ^ (r & 7)) << 3);
    __half* lAp = lA + tid * 8;
    __half* lBp = lB + tid * 8;
    const int wr = (wave & 1) << 6;
    const int wc = (wave >> 1) << 6;
    const int l15 = lane & 15, quad = lane >> 4;

    f32x4 acc[4][4] = {};

    for (int kt = 0; kt < 128; kt += 64) {
#pragma unroll
        for (int i = 0; i < 4; ++i) {
            GLOAD_LDS16(gA + (long)i * 32 * CDIM, lAp + i * 2048);
            GLOAD_LDS16(gB + (long)i * 32 * 4096, lBp + i * 2048);
        }
        gA += 64; gB += 64;
        __syncthreads();
#pragma unroll
        for (int kk = 0; kk < 2; ++kk) {
            f16x8 af[4], bfr[4];
#pragma unroll
            for (int mi = 0; mi < 4; ++mi) {
                const int m = wr + mi * 16 + l15;
                const int kg = kk * 4 + quad;
                af[mi] = *(const f16x8*)&lA[m * 64 + ((kg ^ (m & 7)) << 3)];
            }
#pragma unroll
            for (int ni = 0; ni < 4; ++ni) {
                const int n = wc + ni * 16 + l15;
                const int kg = kk * 4 + quad;
                bfr[ni] = *(const f16x8*)&lB[n * 64 + ((kg ^ (n & 7)) << 3)];
            }
#pragma unroll
            for (int mi = 0; mi < 4; ++mi)
#pragma unroll
                for (int ni = 0; ni < 4; ++ni)
                    acc[mi][ni] = __builtin_amdgcn_mfma_f32_16x16x32_f16(
                        af[mi], bfr[ni], acc[mi][ni], 0, 0, 0);
        }
        __syncthreads();
    }
    // epilogue: exp2, store fp16 P, row-sum -> atomics
    __half* Ph = P + (long)h * LQ * LKEY;
    const int row0 = bm * 128 + wr + quad * 4;
    const int col0 = bn * 128 + wc + l15;
#pragma unroll
    for (int mi = 0; mi < 4; ++mi) {
#pragma unroll
        for (int rx = 0; rx < 4; ++rx) {
            float rs = 0.f;
#pragma unroll
            for (int ni = 0; ni < 4; ++ni) {
                const float p = __builtin_amdgcn_exp2f(acc[mi][ni][rx] - 10.0f);
                rs += p;
                Ph[(long)(row0 + mi * 16 + rx) * LKEY + col0 + ni * 16] = __float2half(p);
            }
            rs += __shfl_xor(rs, 1);
            rs += __shfl_xor(rs, 2);
            rs += __shfl_xor(rs, 4);
            rs += __shfl_xor(rs, 8);
            if (l15 == 0)
                atomicAdd(&lsum[h * LQ + row0 + mi * 16 + rx], rs);
        }
    }
}

// ---------------------------------------------------------------------------
// PV GEMM: blockIdx.y encodes (head, k-chunk of 2048 keys).
//   Opart[kc][q][h*128+d] = P[h][q, kc*2048:..] . Vt[h*128+d, kc*2048:..]^T
// ---------------------------------------------------------------------------
__global__ __launch_bounds__(256, 2) void pv_gemm(
    const __half* __restrict__ P, const __half* __restrict__ Vt,
    float* __restrict__ Opart)
{
    __shared__ __align__(16) __half lA[128 * 64];
    __shared__ __align__(16) __half lB[128 * 64];
    const int tid  = threadIdx.x;
    const int lane = tid & 63;
    const int wave = tid >> 6;
    const int bm = blockIdx.x;
    const int h  = blockIdx.y >> 1;
    const int kc = blockIdx.y & 1;
    const int r = tid >> 3;
    const int g = tid & 7;
    const __half* gA = P + (long)h * LQ * LKEY + kc * 2048 +
                       (long)(bm * 128 + r) * LKEY + ((g ^ (r & 7)) << 3);
    const __half* gB = Vt + (long)(h * HDIM) * LKEY + kc * 2048 +
                       (long)r * LKEY + ((g ^ (r & 7)) << 3);
    __half* lAp = lA + tid * 8;
    __half* lBp = lB + tid * 8;
    const int wr = (wave & 1) << 6;
    const int wc = (wave >> 1) << 6;
    const int l15 = lane & 15, quad = lane >> 4;

    f32x4 acc[4][4] = {};

    for (int kt = 0; kt < 2048; kt += 64) {
#pragma unroll
        for (int i = 0; i < 4; ++i) {
            GLOAD_LDS16(gA + (long)i * 32 * LKEY, lAp + i * 2048);
            GLOAD_LDS16(gB + (long)i * 32 * LKEY, lBp + i * 2048);
        }
        gA += 64; gB += 64;
        __syncthreads();
#pragma unroll
        for (int kk = 0; kk < 2; ++kk) {
            f16x8 af[4], bfr[4];
#pragma unroll
            for (int mi = 0; mi < 4; ++mi) {
                const int m = wr + mi * 16 + l15;
                const int kg = kk * 4 + quad;
                af[mi] = *(const f16x8*)&lA[m * 64 + ((kg ^ (m & 7)) << 3)];
            }
#pragma unroll
            for (int ni = 0; ni < 4; ++ni) {
                const int n = wc + ni * 16 + l15;
                const int kg = kk * 4 + quad;
                bfr[ni] = *(const f16x8*)&lB[n * 64 + ((kg ^ (n & 7)) << 3)];
            }
#pragma unroll
            for (int mi = 0; mi < 4; ++mi)
#pragma unroll
                for (int ni = 0; ni < 4; ++ni)
                    acc[mi][ni] = __builtin_amdgcn_mfma_f32_16x16x32_f16(
                        af[mi], bfr[ni], acc[mi][ni], 0, 0, 0);
        }
        __syncthreads();
    }
    float* Cp = Opart + (long)kc * LQ * CDIM + h * HDIM;
    const int row0 = bm * 128 + wr + quad * 4;
    const int col0 = wc + l15;
#pragma unroll
    for (int mi = 0; mi < 4; ++mi)
#pragma unroll
        for (int ni = 0; ni < 4; ++ni)
#pragma unroll
            for (int rx = 0; rx < 4; ++rx)
                Cp[(long)(row0 + mi * 16 + rx) * CDIM + col0 + ni * 16] =
                    acc[mi][ni][rx];
}

// ---------------------------------------------------------------------------
// merge: a2[q][c] (attn half of the final-GEMM A) = (Op0+Op1)[q][c] / l[c>>7][q]
// ---------------------------------------------------------------------------
__global__ __launch_bounds__(256) void merge_o(
    const float* __restrict__ Op, const float* __restrict__ lsum,
    __half* __restrict__ a2)
{
    const int row = blockIdx.x;
    const int c0  = threadIdx.x * 8;
    const float inv = 1.0f / lsum[(c0 >> 7) * LQ + row];
    const float* p0 = Op + (long)row * CDIM + c0;
    const float* p1 = p0 + (long)LQ * CDIM;
    union { f16x8 v; _Float16 e[8]; } o;
#pragma unroll
    for (int j = 0; j < 8; ++j)
        o.e[j] = (_Float16)((p0[j] + p1[j]) * inv);
    *(f16x8*)&a2[(long)row * 4096 + c0] = o.v;
}

// ---------------------------------------------------------------------------
// In-place per-(row,head) rmsnorm + depth-rope on fp16 data (D=128).
// ---------------------------------------------------------------------------
__global__ __launch_bounds__(256) void norm_rope(
    __half* __restrict__ X, const float* __restrict__ w,
    int stride, int nrows, int kmode, float oscale)
{
    const int gid  = blockIdx.x * 4 + (threadIdx.x >> 6);
    const int lane = threadIdx.x & 63;
    const int row  = gid >> 4;
    const int h    = gid & 15;
    if (row >= nrows) return;
    __half* p = X + (long)row * stride + h * HDIM;
    float x1 = __half2float(p[lane]);
    float x2 = __half2float(p[lane + 64]);
    float ss = x1 * x1 + x2 * x2;
#pragma unroll
    for (int off = 1; off < 64; off <<= 1) ss += __shfl_xor(ss, off);
    const float rn = rsqrtf(ss * (1.0f / 128.0f) + 1e-6f);
    x1 *= rn * w[lane];
    x2 *= rn * w[lane + 64];
    const int depth = kmode ? (row < LQ ? 0 : 1) : 2;
    const float freq = exp2f(-(float)lane * 0.20762050593045702f);
    const float ang = (float)depth * freq;
    float sn, cs;
    __sincosf(ang, &sn, &cs);
    p[lane]      = __float2half((x1 * cs - x2 * sn) * oscale);
    p[lane + 64] = __float2half((x1 * sn + x2 * cs) * oscale);
}

// ---------------------------------------------------------------------------
// Fallback flash attention (R3), used only if ws_size is too small for P.
// ---------------------------------------------------------------------------
__global__ __launch_bounds__(256, 3) void attn_kernel(
    const __half* __restrict__ Q, const __half* __restrict__ Kb,
    const __half* __restrict__ Vt, __half* __restrict__ Oa)
{
    __shared__ __align__(16) char smem[34816];
    __half* pL = (__half*)smem;
    float*  Os = (float*)smem;
    float*  ml = (float*)(smem + 33792);

    const int lane = threadIdx.x & 63;
    const int wave = threadIdx.x >> 6;
    const int l15  = lane & 15;
    const int quad = lane >> 4;

    const int id   = blockIdx.y * 64 + blockIdx.x;
    const int h    = (id & 7) * 2 + ((id >> 3) & 1);
    const int qb   = id >> 4;
    const int q0   = qb * 32;

    f16x8 aq[2][4];
#pragma unroll
    for (int mt = 0; mt < 2; ++mt)
#pragma unroll
        for (int ks = 0; ks < 4; ++ks)
            aq[mt][ks] = *(const f16x8*)&Q[(long)(q0 + mt * 16 + l15) * CDIM +
                                           h * HDIM + ks * 32 + quad * 8];

    f32x4 accO[2][8] = {};
    f32x4 l_acc[2] = {};

    const int wbase = wave * 16;
    for (int t = 0; t < 16; ++t) {
        const int kt = wbase + t;
        const __half* kbase = Kb + (long)(kt * 64) * 4096 + h * HDIM;
        f32x4 s[2][4];
#pragma unroll
        for (int mt = 0; mt < 2; ++mt)
#pragma unroll
            for (int nt = 0; nt < 4; ++nt)
                s[mt][nt] = (f32x4){-10.f, -10.f, -10.f, -10.f};
#pragma unroll
        for (int nt = 0; nt < 4; ++nt) {
            const __half* krow = kbase + (long)(nt * 16 + l15) * 4096 + quad * 8;
            f16x8 kf0 = *(const f16x8*)(krow);
            f16x8 kf1 = *(const f16x8*)(krow + 32);
            f16x8 kf2 = *(const f16x8*)(krow + 64);
            f16x8 kf3 = *(const f16x8*)(krow + 96);
#pragma unroll
            for (int mt = 0; mt < 2; ++mt) {
                s[mt][nt] = __builtin_amdgcn_mfma_f32_16x16x32_f16(aq[mt][0], kf0, s[mt][nt], 0, 0, 0);
                s[mt][nt] = __builtin_amdgcn_mfma_f32_16x16x32_f16(aq[mt][1], kf1, s[mt][nt], 0, 0, 0);
                s[mt][nt] = __builtin_amdgcn_mfma_f32_16x16x32_f16(aq[mt][2], kf2, s[mt][nt], 0, 0, 0);
                s[mt][nt] = __builtin_amdgcn_mfma_f32_16x16x32_f16(aq[mt][3], kf3, s[mt][nt], 0, 0, 0);
            }
        }
#pragma unroll
        for (int mt = 0; mt < 2; ++mt)
#pragma unroll
            for (int nt = 0; nt < 4; ++nt)
#pragma unroll
                for (int r2 = 0; r2 < 4; ++r2) {
                    const float p = __builtin_amdgcn_exp2f(s[mt][nt][r2]);
                    l_acc[mt][r2] += p;
                    pL[((wave * 2 + mt) * 16 + quad * 4 + r2) * 72 + nt * 16 + l15] =
                        __float2half(p);
                }
        f16x8 ap[2][2];
#pragma unroll
        for (int mt = 0; mt < 2; ++mt) {
            ap[mt][0] = *(const f16x8*)&pL[((wave * 2 + mt) * 16 + l15) * 72 + quad * 8];
            ap[mt][1] = *(const f16x8*)&pL[((wave * 2 + mt) * 16 + l15) * 72 + 32 + quad * 8];
        }
        const __half* vbase = Vt + (long)(h * HDIM) * LKEY + kt * 64;
#pragma unroll
        for (int nt2 = 0; nt2 < 8; ++nt2) {
            const __half* vrow = vbase + (long)(nt2 * 16 + l15) * LKEY + quad * 8;
            f16x8 v0 = *(const f16x8*)(vrow);
            f16x8 v1 = *(const f16x8*)(vrow + 32);
            accO[0][nt2] = __builtin_amdgcn_mfma_f32_16x16x32_f16(ap[0][0], v0, accO[0][nt2], 0, 0, 0);
            accO[0][nt2] = __builtin_amdgcn_mfma_f32_16x16x32_f16(ap[0][1], v1, accO[0][nt2], 0, 0, 0);
            accO[1][nt2] = __builtin_amdgcn_mfma_f32_16x16x32_f16(ap[1][0], v0, accO[1][nt2], 0, 0, 0);
            accO[1][nt2] = __builtin_amdgcn_mfma_f32_16x16x32_f16(ap[1][1], v1, accO[1][nt2], 0, 0, 0);
        }
    }

#pragma unroll
    for (int mt = 0; mt < 2; ++mt)
#pragma unroll
        for (int r2 = 0; r2 < 4; ++r2) {
            float v = l_acc[mt][r2];
            v += __shfl_xor(v, 1);
            v += __shfl_xor(v, 2);
            v += __shfl_xor(v, 4);
            v += __shfl_xor(v, 8);
            l_acc[mt][r2] = v;
        }
    if (l15 == 0) {
#pragma unroll
        for (int mt = 0; mt < 2; ++mt)
#pragma unroll
            for (int r2 = 0; r2 < 4; ++r2)
                ml[(wave * 2 + mt) * 16 + quad * 4 + r2] = l_acc[mt][r2];
    }
    __syncthreads();

    for (int mt = 0; mt < 2; ++mt) {
#pragma unroll
        for (int nt2 = 0; nt2 < 8; ++nt2)
#pragma unroll
            for (int r2 = 0; r2 < 4; ++r2)
                Os[wave * 2112 + (quad * 4 + r2) * 132 + nt2 * 16 + l15] =
                    accO[mt][nt2][r2];
        __syncthreads();
        {
            const int row = threadIdx.x >> 4;
            const int col = (threadIdx.x & 15) << 3;
            float lg = 0.f;
#pragma unroll
            for (int w2 = 0; w2 < 4; ++w2)
                lg += ml[(w2 * 2 + mt) * 16 + row];
            const float inv = 1.0f / lg;
            float acc8[8] = {};
#pragma unroll
            for (int w2 = 0; w2 < 4; ++w2) {
                const float* p = &Os[w2 * 2112 + row * 132 + col];
                f32x4 a = *(const f32x4*)p;
                f32x4 b = *(const f32x4*)(p + 4);
#pragma unroll
                for (int j = 0; j < 4; ++j) { acc8[j] += a[j]; acc8[j + 4] += b[j]; }
            }
            union { f16x8 v; _Float16 e[8]; } o;
#pragma unroll
            for (int j = 0; j < 8; ++j) o.e[j] = (_Float16)(acc8[j] * inv);
            *(f16x8*)&Oa[(long)(q0 + mt * 16 + row) * 4096 + h * HDIM + col] = o.v;
        }
        __syncthreads();
    }
}

// ---------------------------------------------------------------------------
// helpers
// ---------------------------------------------------------------------------
__global__ void cast_h4(const float* __restrict__ in, __half* __restrict__ out, int n) {
    const int i = (blockIdx.x * 256 + threadIdx.x) << 2;
    if (i >= n) return;
    const float4 v = *(const float4*)&in[i];
    out[i]     = __float2half(v.x);
    out[i + 1] = __float2half(v.y);
    out[i + 2] = __float2half(v.z);
    out[i + 3] = __float2half(v.w);
}

__global__ void cast_wo(const float* __restrict__ in, __half* __restrict__ out) {
    const int idx = blockIdx.x * 256 + threadIdx.x;
    const int o = idx >> 11, c = idx & 2047;
    out[((long)o << 12) + c] = __float2half(in[idx]);
}

template <typename InT>
__global__ __launch_bounds__(256) void transpose_h(
    const InT* __restrict__ in, long inStride, long inOff,
    __half* __restrict__ out, long outStride, long outOff)
{
    __shared__ float t[64][65];
    const long r0 = (long)blockIdx.x * 64;
    const long c0 = (long)blockIdx.y * 64;
    const int tj = threadIdx.x & 63;
    const int ti = threadIdx.x >> 6;
#pragma unroll
    for (int it = 0; it < 16; ++it) {
        const int i = it * 4 + ti;
        t[i][tj] = toF(in[(r0 + i) * inStride + inOff + c0 + tj]);
    }
    __syncthreads();
#pragma unroll
    for (int it = 0; it < 16; ++it) {
        const int i = it * 4 + ti;
        out[(c0 + i) * outStride + outOff + r0 + tj] = __float2half(t[tj][i]);
    }
}

__global__ void sin_feat(const float* __restrict__ sw1, const float* __restrict__ sb1,
                         __half* __restrict__ a2) {
    const int idx = blockIdx.x * 256 + threadIdx.x;
    const int l = idx >> 11, c = idx & 2047;
    const float coord = -1.0f + (2.0f / 2047.0f) * (float)l;
    const float v = sinf(30.0f * (coord * sw1[c] + sb1[c]));
    a2[((long)l << 12) + 2048 + c] = __float2half(v);
}

__global__ __launch_bounds__(256) void final_norm(
    const float* __restrict__ out2, const float* __restrict__ x,
    const float* __restrict__ sb2, const float* __restrict__ on_w,
    float* __restrict__ y)
{
    const int row = blockIdx.x;
    const float* o = out2 + (long)row * CDIM;
    float v[8];
    float ss = 0.f;
#pragma unroll
    for (int i = 0; i < 8; ++i) {
        const int c = threadIdx.x + i * 256;
        const float t = o[c] + sb2[c];
        v[i] = t;
        ss += t * t;
    }
#pragma unroll
    for (int off = 1; off < 64; off <<= 1) ss += __shfl_xor(ss, off);
    __shared__ float red[4];
    const int lane = threadIdx.x & 63, wv = threadIdx.x >> 6;
    if (lane == 0) red[wv] = ss;
    __syncthreads();
    const float tot = red[0] + red[1] + red[2] + red[3];
    const float rn = rsqrtf(tot * (1.0f / 2048.0f) + 1e-6f);
#pragma unroll
    for (int i = 0; i < 8; ++i) {
        const int c = threadIdx.x + i * 256;
        y[(long)row * CDIM + c] = x[(long)row * CDIM + c] + v[i] * rn * on_w[c];
    }
}

// ---------------------------------------------------------------------------
extern "C" void kernel_launch(void* const* d_in, const int* in_sizes, int n_in,
                              void* d_out, int out_size, void* d_ws, size_t ws_size,
                              hipStream_t stream) {
    const float* x    = (const float*)d_in[0];
    const float* h0   = (const float*)d_in[1];
    const float* h1   = (const float*)d_in[2];
    const float* h2   = (const float*)d_in[3];
    const float* Wq   = (const float*)d_in[4];
    const float* Wk   = (const float*)d_in[5];
    const float* Wv   = (const float*)d_in[6];
    const float* Wo   = (const float*)d_in[7];
    const float* qn_w = (const float*)d_in[8];
    const float* kn_w = (const float*)d_in[9];
    const float* on_w = (const float*)d_in[10];
    const float* sw1  = (const float*)d_in[11];
    const float* sb1  = (const float*)d_in[12];
    const float* sw2  = (const float*)d_in[13];
    const float* sb2  = (const float*)d_in[14];
    float* y = (float*)d_out;

    const size_t MB = 1ull << 20;
    char* w = (char*)d_ws;
    __half* xq  = (__half*)(w);             //  8 MB  h2 fp16
    __half* xkv = (__half*)(w + 8 * MB);    // 16 MB  [h0;h1] fp16
    __half* wqh = (__half*)(w + 24 * MB);   //  8 MB  Wq fp16
    __half* wkv = (__half*)(w + 32 * MB);   // 16 MB  [Wk;Wv] fp16
    __half* qf  = (__half*)(w + 48 * MB);   //  8 MB  Q proj -> normed q
    __half* kvf = (__half*)(w + 56 * MB);   // 32 MB  [K|V] proj (4096x4096)
    __half* vT  = (__half*)(w + 88 * MB);   // 16 MB  V transposed (2048x4096)
    __half* a2  = (__half*)(w + 104 * MB);  // 16 MB  [attn_out | sin_feat]
    __half* b2  = (__half*)(w + 120 * MB);  // 16 MB  [Wo | sw2^T]
    float* out2 = (float*)(w + 136 * MB);   // 16 MB  final GEMM out
    // two-GEMM attention extras (overlays + tail):
    float*  Opart = (float*)(w);            // 32 MB  over dead cast buffers
    float*  lsum  = (float*)(w + 32 * MB);  // 128 KB over dead wkv region
    __half* Pbuf  = (__half*)(w + 152 * MB);// 256 MB fresh
    const bool bigws = ws_size >= (size_t)408 * MB;
    (void)in_sizes; (void)n_in; (void)out_size;

    const int n4 = 2048 * 2048;
    cast_h4<<<n4 / 1024, 256, 0, stream>>>(h2, xq, n4);
    cast_h4<<<n4 / 1024, 256, 0, stream>>>(h0, xkv, n4);
    cast_h4<<<n4 / 1024, 256, 0, stream>>>(h1, xkv + n4, n4);
    cast_h4<<<n4 / 1024, 256, 0, stream>>>(Wq, wqh, n4);
    cast_h4<<<n4 / 1024, 256, 0, stream>>>(Wk, wkv, n4);
    cast_h4<<<n4 / 1024, 256, 0, stream>>>(Wv, wkv + n4, n4);
    cast_wo<<<n4 / 256, 256, 0, stream>>>(Wo, b2);
    transpose_h<float><<<dim3(32, 32), 256, 0, stream>>>(sw2, 2048, 0, b2, 4096, 2048);
    sin_feat<<<n4 / 256, 256, 0, stream>>>(sw1, sb1, a2);

    gemm_bt<__half><<<dim3(16, 16), 256, 0, stream>>>(xq, wqh, qf, 2048, 2048, 2048, 2048);
    gemm_bt<__half><<<dim3(32, 32), 256, 0, stream>>>(xkv, wkv, kvf, 2048, 2048, 4096, 2048);

    // q pre-scale = log2(e)/sqrt(D): scores in log2 domain for exp2
    norm_rope<<<8192, 256, 0, stream>>>(qf, qn_w, 2048, 2048, 0, 0.12751743f);
    norm_rope<<<16384, 256, 0, stream>>>(kvf, kn_w, 4096, 4096, 1, 1.0f);
    transpose_h<__half><<<dim3(64, 32), 256, 0, stream>>>(kvf, 4096, 2048, vT, 4096, 0);

    if (bigws) {
        (void)hipMemsetAsync(lsum, 0, NHEAD * LQ * sizeof(float), stream);
        sgemm_exp<<<dim3(16, 32, 16), 256, 0, stream>>>(qf, kvf, Pbuf, lsum);
        pv_gemm<<<dim3(16, 32), 256, 0, stream>>>(Pbuf, vT, Opart);
        merge_o<<<2048, 256, 0, stream>>>(Opart, lsum, a2);
    } else {
        attn_kernel<<<dim3(64, 16), 256, 0, stream>>>(qf, kvf, vT, a2);
    }

    gemm_bt<float><<<dim3(16, 16), 256, 0, stream>>>(a2, b2, out2, 4096, 4096, 2048, 4096);
    final_norm<<<2048, 256, 0, stream>>>(out2, x, sb2, on_w, y);
}

// Round 6
// 519.925 us; speedup vs baseline: 1.3148x; 1.3148x over previous
//
#include <hip/hip_runtime.h>
#include <hip/hip_fp16.h>

// Problem constants: B=1, L=2048, C=2048, H=16, D=128, keys = 2L = 4096
#define LQ 2048
#define CDIM 2048
#define NHEAD 16
#define HDIM 128
#define LKEY 4096

typedef _Float16 f16x8 __attribute__((ext_vector_type(8)));
typedef float f32x4 __attribute__((ext_vector_type(4)));

#define GLOAD_LDS16(g, s) __builtin_amdgcn_global_load_lds( \
    (const __attribute__((address_space(1))) void*)(g),     \
    (__attribute__((address_space(3))) void*)(s), 16, 0, 0)

#define MFMA16(a, b, c) __builtin_amdgcn_mfma_f32_16x16x32_f16(a, b, c, 0, 0, 0)

__device__ __forceinline__ void storeC(float* p, float v) { *p = v; }
__device__ __forceinline__ void storeC(__half* p, float v) { *p = __float2half(v); }
__device__ __forceinline__ float toF(float v) { return v; }
__device__ __forceinline__ float toF(__half v) { return __half2float(v); }

// ---------------------------------------------------------------------------
// C[128bm:+128, 128bn:+128] = A[*,0:K] * B[*,0:K]^T  (fp16 in, fp32 acc)
// 128x128 tile, BK=64, 4 waves, 4x4 acc/wave, global_load_lds staging.
// ---------------------------------------------------------------------------
template <typename OutT>
__global__ __launch_bounds__(256, 2) void gemm_bt(
    const __half* __restrict__ A, const __half* __restrict__ B,
    OutT* __restrict__ C, int lda, int ldb, int ldc, int K)
{
    __shared__ __align__(16) __half lA[128 * 64];
    __shared__ __align__(16) __half lB[128 * 64];
    const int tid  = threadIdx.x;
    const int lane = tid & 63;
    const int wave = tid >> 6;
    const int bm = blockIdx.x, bn = blockIdx.y;
    const int r = tid >> 3;     // 0..31: row within 32-row staging slab
    const int g = tid & 7;      // 8-elem col group
    const __half* gA = A + (long)(bm * 128 + r) * lda + ((g ^ (r & 7)) << 3);
    const __half* gB = B + (long)(bn * 128 + r) * ldb + ((g ^ (r & 7)) << 3);
    __half* lAp = lA + tid * 8;
    __half* lBp = lB + tid * 8;
    const int wr = (wave & 1) << 6;
    const int wc = (wave >> 1) << 6;
    const int l15 = lane & 15, quad = lane >> 4;

    f32x4 acc[4][4] = {};

    for (int kt = 0; kt < K; kt += 64) {
#pragma unroll
        for (int i = 0; i < 4; ++i) {
            GLOAD_LDS16(gA + (long)i * 32 * lda, lAp + i * 2048);
            GLOAD_LDS16(gB + (long)i * 32 * ldb, lBp + i * 2048);
        }
        gA += 64; gB += 64;
        __syncthreads();
#pragma unroll
        for (int kk = 0; kk < 2; ++kk) {
            f16x8 af[4], bfr[4];
#pragma unroll
            for (int mi = 0; mi < 4; ++mi) {
                const int m = wr + mi * 16 + l15;
                const int kg = kk * 4 + quad;
                af[mi] = *(const f16x8*)&lA[m * 64 + ((kg ^ (m & 7)) << 3)];
            }
#pragma unroll
            for (int ni = 0; ni < 4; ++ni) {
                const int n = wc + ni * 16 + l15;
                const int kg = kk * 4 + quad;
                bfr[ni] = *(const f16x8*)&lB[n * 64 + ((kg ^ (n & 7)) << 3)];
            }
#pragma unroll
            for (int mi = 0; mi < 4; ++mi)
#pragma unroll
                for (int ni = 0; ni < 4; ++ni)
                    acc[mi][ni] = MFMA16(af[mi], bfr[ni], acc[mi][ni]);
        }
        __syncthreads();
    }
    const int row0 = bm * 128 + wr + quad * 4;
    const int col0 = bn * 128 + wc + l15;
#pragma unroll
    for (int mi = 0; mi < 4; ++mi)
#pragma unroll
        for (int ni = 0; ni < 4; ++ni)
#pragma unroll
            for (int rx = 0; rx < 4; ++rx)
                storeC(&C[(long)(row0 + mi * 16 + rx) * ldc + col0 + ni * 16],
                       acc[mi][ni][rx]);
}

// ---------------------------------------------------------------------------
// Fused attention tile kernel (max-free softmax, log2-domain scores).
// Grid (16 q-tiles, 32 = head*2 + kc). Block = 4 waves, 128 q-rows, 2048 keys.
// Per key-step (64 keys): stage K-tile [64][128] + V-tile [128][64] in LDS
// via global_load_lds (shared by all 4 waves), QK MFMA -> exp2(s-10) ->
// P via per-wave LDS slab -> PV MFMA. Partial l via atomics, partial O fp32.
// ---------------------------------------------------------------------------
__global__ __launch_bounds__(256, 2) void attn_tile(
    const __half* __restrict__ Qf,  // [2048][2048] normed+roped, log2-scaled
    const __half* __restrict__ Kf,  // kvf [4096][4096]; K in cols 0..2047
    const __half* __restrict__ Vt,  // [2048][4096]  Vt[h*128+d][key]
    float* __restrict__ Opart,      // [2][2048][2048]
    float* __restrict__ lsum)       // [16][2048]
{
    __shared__ __align__(16) __half lK[64 * 128];   // 16 KB
    __shared__ __align__(16) __half lV[128 * 64];   // 16 KB
    __shared__ __align__(16) __half pL[4 * 2 * 16 * 72];  // 18 KB

    const int tid  = threadIdx.x;
    const int lane = tid & 63;
    const int wave = tid >> 6;
    const int l15  = lane & 15;
    const int quad = lane >> 4;
    const int h  = blockIdx.y >> 1;
    const int kc = blockIdx.y & 1;
    const int q0 = blockIdx.x * 128 + wave * 32;   // this wave's 32 q-rows

    // Q A-fragments: A[m=l15][k=ks*32+quad*8+j]
    f16x8 aq[2][4];
#pragma unroll
    for (int mt = 0; mt < 2; ++mt)
#pragma unroll
        for (int ks = 0; ks < 4; ++ks)
            aq[mt][ks] = *(const f16x8*)&Qf[(long)(q0 + mt * 16 + l15) * CDIM +
                                            h * HDIM + ks * 32 + quad * 8];

    // staging pointers. LDS[r][g] = global[r][g ^ (r & mask)] (XOR swizzle in
    // the SOURCE address; LDS dest is wave-uniform base + lane*16).
    const int rK = tid >> 4;          // K row 0..15 (+16/issue)
    const int gK = tid & 15;          // 16 groups of 8 halves
    const __half* srcK = Kf + (long)(kc * 2048 + rK) * 4096 + h * HDIM +
                         ((gK ^ (rK & 15)) << 3);
    const int rV = tid >> 3;          // V row (d) 0..31 (+32/issue)
    const int gV = tid & 7;           // 8 groups of 8 halves
    const __half* srcV = Vt + (long)(h * HDIM + rV) * (long)LKEY + kc * 2048 +
                         ((gV ^ (rV & 7)) << 3);
    __half* dstK = lK + tid * 8;
    __half* dstV = lV + tid * 8;

    f32x4 accO[2][8] = {};
    f32x4 l_acc[2] = {};

    for (int st = 0; st < 32; ++st) {
#pragma unroll
        for (int i = 0; i < 4; ++i) {
            GLOAD_LDS16(srcK + (long)(st * 64 + i * 16) * 4096, dstK + i * 2048);
            GLOAD_LDS16(srcV + (long)i * 32 * LKEY + st * 64, dstV + i * 2048);
        }
        __syncthreads();
        // ---- QK^T (acc init -10 folds the exp2 bias) ----
        f32x4 s[2][4];
#pragma unroll
        for (int mt = 0; mt < 2; ++mt)
#pragma unroll
            for (int nt = 0; nt < 4; ++nt)
                s[mt][nt] = (f32x4){-10.f, -10.f, -10.f, -10.f};
#pragma unroll
        for (int nt = 0; nt < 4; ++nt) {
            const int n = nt * 16 + l15;
#pragma unroll
            for (int ks = 0; ks < 4; ++ks) {
                const f16x8 kf = *(const f16x8*)
                    &lK[n * 128 + (((ks * 4 + quad) ^ (n & 15)) << 3)];
                s[0][nt] = MFMA16(aq[0][ks], kf, s[0][nt]);
                s[1][nt] = MFMA16(aq[1][ks], kf, s[1][nt]);
            }
        }
        // ---- P = exp2(s), accumulate l, stage P (per-wave slab) ----
#pragma unroll
        for (int mt = 0; mt < 2; ++mt)
#pragma unroll
            for (int nt = 0; nt < 4; ++nt)
#pragma unroll
                for (int r2 = 0; r2 < 4; ++r2) {
                    const float p = __builtin_amdgcn_exp2f(s[mt][nt][r2]);
                    l_acc[mt][r2] += p;
                    pL[((wave * 2 + mt) * 16 + quad * 4 + r2) * 72 +
                       nt * 16 + l15] = __float2half(p);
                }
        // ---- PV ----
        f16x8 ap[2][2];
#pragma unroll
        for (int mt = 0; mt < 2; ++mt) {
            ap[mt][0] = *(const f16x8*)&pL[((wave * 2 + mt) * 16 + l15) * 72 + quad * 8];
            ap[mt][1] = *(const f16x8*)&pL[((wave * 2 + mt) * 16 + l15) * 72 + 32 + quad * 8];
        }
#pragma unroll
        for (int nt2 = 0; nt2 < 8; ++nt2) {
            const int n2 = nt2 * 16 + l15;
            const f16x8 v0 = *(const f16x8*)&lV[n2 * 64 + ((quad ^ (n2 & 7)) << 3)];
            const f16x8 v1 = *(const f16x8*)&lV[n2 * 64 + (((4 + quad) ^ (n2 & 7)) << 3)];
            accO[0][nt2] = MFMA16(ap[0][0], v0, accO[0][nt2]);
            accO[0][nt2] = MFMA16(ap[0][1], v1, accO[0][nt2]);
            accO[1][nt2] = MFMA16(ap[1][0], v0, accO[1][nt2]);
            accO[1][nt2] = MFMA16(ap[1][1], v1, accO[1][nt2]);
        }
        __syncthreads();
    }

    // ---- l: reduce across the 16 l15 lanes, publish via atomics ----
#pragma unroll
    for (int mt = 0; mt < 2; ++mt)
#pragma unroll
        for (int r2 = 0; r2 < 4; ++r2) {
            float v = l_acc[mt][r2];
            v += __shfl_xor(v, 1);
            v += __shfl_xor(v, 2);
            v += __shfl_xor(v, 4);
            v += __shfl_xor(v, 8);
            if (l15 == 0)
                atomicAdd(&lsum[h * LQ + q0 + mt * 16 + quad * 4 + r2], v);
        }
    // ---- O partial (fp32) ----
    float* Cp = Opart + (long)kc * LQ * CDIM + h * HDIM;
#pragma unroll
    for (int mt = 0; mt < 2; ++mt)
#pragma unroll
        for (int nt2 = 0; nt2 < 8; ++nt2)
#pragma unroll
            for (int rx = 0; rx < 4; ++rx)
                Cp[(long)(q0 + mt * 16 + quad * 4 + rx) * CDIM + nt2 * 16 + l15] =
                    accO[mt][nt2][rx];
}

// ---------------------------------------------------------------------------
// merge: a2[q][c] = (Op0+Op1)[q][c] / lsum[c>>7][q]   (fp16 out)
// ---------------------------------------------------------------------------
__global__ __launch_bounds__(256) void merge_o(
    const float* __restrict__ Op, const float* __restrict__ lsum,
    __half* __restrict__ a2)
{
    const int row = blockIdx.x;
    const int c0  = threadIdx.x * 8;
    const float inv = 1.0f / lsum[(c0 >> 7) * LQ + row];
    const float* p0 = Op + (long)row * CDIM + c0;
    const float* p1 = p0 + (long)LQ * CDIM;
    union { f16x8 v; _Float16 e[8]; } o;
#pragma unroll
    for (int j = 0; j < 8; ++j)
        o.e[j] = (_Float16)((p0[j] + p1[j]) * inv);
    *(f16x8*)&a2[(long)row * 4096 + c0] = o.v;
}

// ---------------------------------------------------------------------------
// In-place per-(row,head) rmsnorm + depth-rope on fp16 data (D=128).
// ---------------------------------------------------------------------------
__global__ __launch_bounds__(256) void norm_rope(
    __half* __restrict__ X, const float* __restrict__ w,
    int stride, int nrows, int kmode, float oscale)
{
    const int gid  = blockIdx.x * 4 + (threadIdx.x >> 6);
    const int lane = threadIdx.x & 63;
    const int row  = gid >> 4;
    const int h    = gid & 15;
    if (row >= nrows) return;
    __half* p = X + (long)row * stride + h * HDIM;
    float x1 = __half2float(p[lane]);
    float x2 = __half2float(p[lane + 64]);
    float ss = x1 * x1 + x2 * x2;
#pragma unroll
    for (int off = 1; off < 64; off <<= 1) ss += __shfl_xor(ss, off);
    const float rn = rsqrtf(ss * (1.0f / 128.0f) + 1e-6f);
    x1 *= rn * w[lane];
    x2 *= rn * w[lane + 64];
    const int depth = kmode ? (row < LQ ? 0 : 1) : 2;
    const float freq = exp2f(-(float)lane * 0.20762050593045702f);
    const float ang = (float)depth * freq;
    float sn, cs;
    __sincosf(ang, &sn, &cs);
    p[lane]      = __float2half((x1 * cs - x2 * sn) * oscale);
    p[lane + 64] = __float2half((x1 * sn + x2 * cs) * oscale);
}

// ---------------------------------------------------------------------------
// helpers
// ---------------------------------------------------------------------------
__global__ void cast_h4(const float* __restrict__ in, __half* __restrict__ out, int n) {
    const int i = (blockIdx.x * 256 + threadIdx.x) << 2;
    if (i >= n) return;
    const float4 v = *(const float4*)&in[i];
    out[i]     = __float2half(v.x);
    out[i + 1] = __float2half(v.y);
    out[i + 2] = __float2half(v.z);
    out[i + 3] = __float2half(v.w);
}

__global__ void cast_wo(const float* __restrict__ in, __half* __restrict__ out) {
    const int idx = blockIdx.x * 256 + threadIdx.x;
    const int o = idx >> 11, c = idx & 2047;
    out[((long)o << 12) + c] = __float2half(in[idx]);
}

template <typename InT>
__global__ __launch_bounds__(256) void transpose_h(
    const InT* __restrict__ in, long inStride, long inOff,
    __half* __restrict__ out, long outStride, long outOff)
{
    __shared__ float t[64][65];
    const long r0 = (long)blockIdx.x * 64;
    const long c0 = (long)blockIdx.y * 64;
    const int tj = threadIdx.x & 63;
    const int ti = threadIdx.x >> 6;
#pragma unroll
    for (int it = 0; it < 16; ++it) {
        const int i = it * 4 + ti;
        t[i][tj] = toF(in[(r0 + i) * inStride + inOff + c0 + tj]);
    }
    __syncthreads();
#pragma unroll
    for (int it = 0; it < 16; ++it) {
        const int i = it * 4 + ti;
        out[(c0 + i) * outStride + outOff + r0 + tj] = __float2half(t[tj][i]);
    }
}

__global__ void sin_feat(const float* __restrict__ sw1, const float* __restrict__ sb1,
                         __half* __restrict__ a2) {
    const int idx = blockIdx.x * 256 + threadIdx.x;
    const int l = idx >> 11, c = idx & 2047;
    const float coord = -1.0f + (2.0f / 2047.0f) * (float)l;
    const float v = sinf(30.0f * (coord * sw1[c] + sb1[c]));
    a2[((long)l << 12) + 2048 + c] = __float2half(v);
}

__global__ __launch_bounds__(256) void final_norm(
    const float* __restrict__ out2, const float* __restrict__ x,
    const float* __restrict__ sb2, const float* __restrict__ on_w,
    float* __restrict__ y)
{
    const int row = blockIdx.x;
    const float* o = out2 + (long)row * CDIM;
    float v[8];
    float ss = 0.f;
#pragma unroll
    for (int i = 0; i < 8; ++i) {
        const int c = threadIdx.x + i * 256;
        const float t = o[c] + sb2[c];
        v[i] = t;
        ss += t * t;
    }
#pragma unroll
    for (int off = 1; off < 64; off <<= 1) ss += __shfl_xor(ss, off);
    __shared__ float red[4];
    const int lane = threadIdx.x & 63, wv = threadIdx.x >> 6;
    if (lane == 0) red[wv] = ss;
    __syncthreads();
    const float tot = red[0] + red[1] + red[2] + red[3];
    const float rn = rsqrtf(tot * (1.0f / 2048.0f) + 1e-6f);
#pragma unroll
    for (int i = 0; i < 8; ++i) {
        const int c = threadIdx.x + i * 256;
        y[(long)row * CDIM + c] = x[(long)row * CDIM + c] + v[i] * rn * on_w[c];
    }
}

// ---------------------------------------------------------------------------
extern "C" void kernel_launch(void* const* d_in, const int* in_sizes, int n_in,
                              void* d_out, int out_size, void* d_ws, size_t ws_size,
                              hipStream_t stream) {
    const float* x    = (const float*)d_in[0];
    const float* h0   = (const float*)d_in[1];
    const float* h1   = (const float*)d_in[2];
    const float* h2   = (const float*)d_in[3];
    const float* Wq   = (const float*)d_in[4];
    const float* Wk   = (const float*)d_in[5];
    const float* Wv   = (const float*)d_in[6];
    const float* Wo   = (const float*)d_in[7];
    const float* qn_w = (const float*)d_in[8];
    const float* kn_w = (const float*)d_in[9];
    const float* on_w = (const float*)d_in[10];
    const float* sw1  = (const float*)d_in[11];
    const float* sb1  = (const float*)d_in[12];
    const float* sw2  = (const float*)d_in[13];
    const float* sb2  = (const float*)d_in[14];
    float* y = (float*)d_out;

    const size_t MB = 1ull << 20;
    char* w = (char*)d_ws;
    __half* xq  = (__half*)(w);             //  8 MB  h2 fp16        (dead after Q gemm)
    __half* xkv = (__half*)(w + 8 * MB);    // 16 MB  [h0;h1] fp16   (dead after KV gemm)
    __half* wqh = (__half*)(w + 24 * MB);   //  8 MB  Wq fp16        (dead after Q gemm)
    __half* wkv = (__half*)(w + 32 * MB);   // 16 MB  [Wk;Wv] fp16   (dead after KV gemm)
    __half* qf  = (__half*)(w + 48 * MB);   //  8 MB  Q proj -> normed q
    __half* kvf = (__half*)(w + 56 * MB);   // 32 MB  [K|V] proj (4096x4096)
    __half* vT  = (__half*)(w + 88 * MB);   // 16 MB  V transposed (2048x4096)
    __half* a2  = (__half*)(w + 104 * MB);  // 16 MB  [attn_out | sin_feat]
    __half* b2  = (__half*)(w + 120 * MB);  // 16 MB  [Wo | sw2^T]
    float* out2 = (float*)(w + 136 * MB);   // 16 MB  final GEMM out
    float* Opart = (float*)(w);             // 32 MB  overlays xq/xkv/wqh (dead)
    float* lsum  = (float*)(w + 32 * MB);   // 128 KB overlays wkv (dead)
    (void)in_sizes; (void)n_in; (void)out_size; (void)ws_size;

    const int n4 = 2048 * 2048;
    cast_h4<<<n4 / 1024, 256, 0, stream>>>(h2, xq, n4);
    cast_h4<<<n4 / 1024, 256, 0, stream>>>(h0, xkv, n4);
    cast_h4<<<n4 / 1024, 256, 0, stream>>>(h1, xkv + n4, n4);
    cast_h4<<<n4 / 1024, 256, 0, stream>>>(Wq, wqh, n4);
    cast_h4<<<n4 / 1024, 256, 0, stream>>>(Wk, wkv, n4);
    cast_h4<<<n4 / 1024, 256, 0, stream>>>(Wv, wkv + n4, n4);
    cast_wo<<<n4 / 256, 256, 0, stream>>>(Wo, b2);
    transpose_h<float><<<dim3(32, 32), 256, 0, stream>>>(sw2, 2048, 0, b2, 4096, 2048);
    sin_feat<<<n4 / 256, 256, 0, stream>>>(sw1, sb1, a2);

    gemm_bt<__half><<<dim3(16, 16), 256, 0, stream>>>(xq, wqh, qf, 2048, 2048, 2048, 2048);
    gemm_bt<__half><<<dim3(32, 32), 256, 0, stream>>>(xkv, wkv, kvf, 2048, 2048, 4096, 2048);

    // q pre-scale = log2(e)/sqrt(D): scores arrive in log2 domain for exp2
    norm_rope<<<8192, 256, 0, stream>>>(qf, qn_w, 2048, 2048, 0, 0.12751743f);
    norm_rope<<<16384, 256, 0, stream>>>(kvf, kn_w, 4096, 4096, 1, 1.0f);
    transpose_h<__half><<<dim3(64, 32), 256, 0, stream>>>(kvf, 4096, 2048, vT, 4096, 0);

    (void)hipMemsetAsync(lsum, 0, NHEAD * LQ * sizeof(float), stream);
    attn_tile<<<dim3(16, 32), 256, 0, stream>>>(qf, kvf, vT, Opart, lsum);
    merge_o<<<2048, 256, 0, stream>>>(Opart, lsum, a2);

    gemm_bt<float><<<dim3(16, 16), 256, 0, stream>>>(a2, b2, out2, 4096, 4096, 2048, 4096);
    final_norm<<<2048, 256, 0, stream>>>(out2, x, sb2, on_w, y);
}